// Round 1
// baseline (1741.888 us; speedup 1.0000x reference)
//
#include <hip/hip_runtime.h>
#include <hip/hip_bf16.h>

#define B_ 4
#define L_ 2
#define P_ 100
#define TPP_ 64
#define D_ 768
#define G_ 10
#define T_ (P_ * TPP_)   // 6400

// ---------------------------------------------------------------------------
// K1a: per-batch effective weights  Weff[b][k][d] = W[D+k][d] + a[b][k]*W[2D+k][d]
// ---------------------------------------------------------------------------
__global__ __launch_bounds__(256) void prep_weights(
    const float* __restrict__ answer, const float* __restrict__ W_p,
    const float* __restrict__ W_t, float* __restrict__ Wp_eff,
    float* __restrict__ Wt_eff)
{
    size_t idx = (size_t)blockIdx.x * 256 + threadIdx.x;  // < B*D*D (exact)
    int d = (int)(idx % D_);
    int k = (int)((idx / D_) % D_);
    int b = (int)(idx / ((size_t)D_ * D_));
    float a = answer[((size_t)b * L_ + (L_ - 1)) * D_ + k];
    size_t o1 = (size_t)(D_ + k) * D_ + d;
    size_t o2 = (size_t)(2 * D_ + k) * D_ + d;
    Wp_eff[idx] = W_p[o1] + a * W_p[o2];
    Wt_eff[idx] = W_t[o1] + a * W_t[o2];
}

// ---------------------------------------------------------------------------
// K1b: per-batch constants  c[b][d] = bias[d] + sum_k a[b][k] * W[k][d]
// ---------------------------------------------------------------------------
__global__ __launch_bounds__(256) void prep_const(
    const float* __restrict__ answer,
    const float* __restrict__ W_p, const float* __restrict__ b_p,
    const float* __restrict__ W_t, const float* __restrict__ b_t,
    float* __restrict__ c_p, float* __restrict__ c_t)
{
    int idx = blockIdx.x * 256 + threadIdx.x;  // < B*D (exact)
    int d = idx % D_;
    int b = idx / D_;
    const float* a = answer + ((size_t)b * L_ + (L_ - 1)) * D_;
    float sp = b_p[d], st = b_t[d];
    for (int k = 0; k < D_; ++k) {
        float av = a[k];
        sp += av * W_p[(size_t)k * D_ + d];
        st += av * W_t[(size_t)k * D_ + d];
    }
    c_p[idx] = sp;
    c_t[idx] = st;
}

// ---------------------------------------------------------------------------
// K2: batched GEMM  ps = q @ Wp_eff[b] + c_p[b] ; ts = q @ Wt_eff[b] + c_t[b]
//     M=T=6400 (per batch), N=768, K=768. BM=BN=64, BK=16, 4x4 microtile.
//     A staged K-major in LDS so fragment reads are float4.
// ---------------------------------------------------------------------------
__global__ __launch_bounds__(256) void gemm_pt(
    const float* __restrict__ qps,
    const float* __restrict__ Wp_eff, const float* __restrict__ Wt_eff,
    const float* __restrict__ c_p, const float* __restrict__ c_t,
    __hip_bfloat16* __restrict__ ps, __hip_bfloat16* __restrict__ ts)
{
    const int tm = blockIdx.x;      // 0..99
    const int tn = blockIdx.y;      // 0..11
    const int b  = blockIdx.z;      // 0..3

    const float* q  = qps + ((size_t)b * L_ + (L_ - 1)) * (size_t)T_ * D_;
    const float* Bp = Wp_eff + (size_t)b * D_ * D_;
    const float* Bt = Wt_eff + (size_t)b * D_ * D_;

    __shared__ float As[16][68];    // [k][m], 68 => 16B-aligned rows, ~2-way banks
    __shared__ float Bsp[16][68];   // [k][n]
    __shared__ float Bst[16][68];

    const int tid = threadIdx.x;
    const int tx = tid & 15, ty = tid >> 4;
    const int row0 = tm * 64, col0 = tn * 64;

    float accP[4][4] = {};
    float accT[4][4] = {};

    for (int k0 = 0; k0 < D_; k0 += 16) {
        const int kk = tid & 15;
        const int rbase = tid >> 4;
#pragma unroll
        for (int i = 0; i < 4; ++i) {
            int r = rbase + 16 * i;
            As[kk][r] = q[(size_t)(row0 + r) * D_ + k0 + kk];
        }
        const int c = tid & 63;
        const int krb = tid >> 6;
#pragma unroll
        for (int i = 0; i < 4; ++i) {
            int kr = krb + 4 * i;
            size_t off = (size_t)(k0 + kr) * D_ + col0 + c;
            Bsp[kr][c] = Bp[off];
            Bst[kr][c] = Bt[off];
        }
        __syncthreads();
#pragma unroll
        for (int kq = 0; kq < 16; ++kq) {
            float4 av = *reinterpret_cast<const float4*>(&As[kq][ty * 4]);
            float4 bp = *reinterpret_cast<const float4*>(&Bsp[kq][tx * 4]);
            float4 bt = *reinterpret_cast<const float4*>(&Bst[kq][tx * 4]);
            const float avv[4] = {av.x, av.y, av.z, av.w};
            const float bpv[4] = {bp.x, bp.y, bp.z, bp.w};
            const float btv[4] = {bt.x, bt.y, bt.z, bt.w};
#pragma unroll
            for (int i = 0; i < 4; ++i)
#pragma unroll
                for (int j = 0; j < 4; ++j) {
                    accP[i][j] += avv[i] * bpv[j];
                    accT[i][j] += avv[i] * btv[j];
                }
        }
        __syncthreads();
    }

#pragma unroll
    for (int i = 0; i < 4; ++i) {
        int r = row0 + ty * 4 + i;
#pragma unroll
        for (int j = 0; j < 4; ++j) {
            int cc = col0 + tx * 4 + j;
            size_t o = (size_t)b * T_ * D_ + (size_t)r * D_ + cc;
            ps[o] = __float2bfloat16(accP[i][j] + c_p[b * D_ + cc]);
            ts[o] = __float2bfloat16(accT[i][j] + c_t[b * D_ + cc]);
        }
    }
}

// ---------------------------------------------------------------------------
// K3: segment max over passages.  sm[b][g][t][d] = max_{p: tid[b][p]==g} ts[b][p*64+t][d]
// One thread per (b,t,d). G=10 running maxes kept in (statically-indexed) regs.
// ---------------------------------------------------------------------------
__global__ __launch_bounds__(256) void segmax_kernel(
    const __hip_bfloat16* __restrict__ ts, const int* __restrict__ table_ids,
    __hip_bfloat16* __restrict__ sm)
{
    int idx = blockIdx.x * 256 + threadIdx.x;  // < B*TPP*D (exact)
    int d = idx % D_;
    int bt = idx / D_;
    int t = bt % TPP_;
    int b = bt / TPP_;

    float m[G_];
#pragma unroll
    for (int g = 0; g < G_; ++g) m[g] = -1e30f;

    const __hip_bfloat16* base = ts + ((size_t)b * T_ + t) * D_ + d;
    for (int p = 0; p < P_; ++p) {
        int g = table_ids[b * P_ + p];
        float v = __bfloat162float(base[(size_t)p * TPP_ * D_]);
#pragma unroll
        for (int gg = 0; gg < G_; ++gg)
            m[gg] = (gg == g) ? fmaxf(m[gg], v) : m[gg];
    }
#pragma unroll
    for (int g = 0; g < G_; ++g)
        sm[(((size_t)b * G_ + g) * TPP_ + t) * D_ + d] = __float2bfloat16(m[g]);
}

// ---------------------------------------------------------------------------
// K4a: h = relu([ps, aggr] @ W1 + b1).  M-tile (64 rows) == one passage, so
//      the concat is just two A-tile sources (k<768 -> ps, else segmax[tid]).
// ---------------------------------------------------------------------------
__global__ __launch_bounds__(256) void gemm_h(
    const __hip_bfloat16* __restrict__ ps, const __hip_bfloat16* __restrict__ sm,
    const int* __restrict__ table_ids, const float* __restrict__ W1,
    const float* __restrict__ b1, __hip_bfloat16* __restrict__ h)
{
    const int bp = blockIdx.x;      // b*P+p, 0..399
    const int tn = blockIdx.y;      // 0..11
    const int b = bp / P_, p = bp % P_;
    const int g = table_ids[bp];

    const __hip_bfloat16* Aps = ps + ((size_t)b * T_ + (size_t)p * TPP_) * D_;
    const __hip_bfloat16* Asg = sm + (((size_t)b * G_ + g) * (size_t)TPP_) * D_;

    __shared__ float As[16][68];
    __shared__ float Bs[16][68];

    const int tid = threadIdx.x;
    const int tx = tid & 15, ty = tid >> 4;
    const int col0 = tn * 64;

    float acc[4][4] = {};

    for (int k0 = 0; k0 < 2 * D_; k0 += 16) {
        const __hip_bfloat16* Asrc = (k0 < D_) ? Aps : Asg;
        const int kb = (k0 < D_) ? k0 : k0 - D_;
        const int kk = tid & 15;
        const int rbase = tid >> 4;
#pragma unroll
        for (int i = 0; i < 4; ++i) {
            int r = rbase + 16 * i;
            As[kk][r] = __bfloat162float(Asrc[(size_t)r * D_ + kb + kk]);
        }
        const int c = tid & 63;
        const int krb = tid >> 6;
#pragma unroll
        for (int i = 0; i < 4; ++i) {
            int kr = krb + 4 * i;
            Bs[kr][c] = W1[(size_t)(k0 + kr) * D_ + col0 + c];
        }
        __syncthreads();
#pragma unroll
        for (int kq = 0; kq < 16; ++kq) {
            float4 av = *reinterpret_cast<const float4*>(&As[kq][ty * 4]);
            float4 bv = *reinterpret_cast<const float4*>(&Bs[kq][tx * 4]);
            const float avv[4] = {av.x, av.y, av.z, av.w};
            const float bvv[4] = {bv.x, bv.y, bv.z, bv.w};
#pragma unroll
            for (int i = 0; i < 4; ++i)
#pragma unroll
                for (int j = 0; j < 4; ++j)
                    acc[i][j] += avv[i] * bvv[j];
        }
        __syncthreads();
    }

#pragma unroll
    for (int i = 0; i < 4; ++i) {
        int r = ty * 4 + i;
#pragma unroll
        for (int j = 0; j < 4; ++j) {
            int cc = col0 + tx * 4 + j;
            float v = acc[i][j] + b1[cc];
            h[((size_t)b * T_ + (size_t)p * TPP_ + r) * D_ + cc] =
                __float2bfloat16(fmaxf(v, 0.0f));
        }
    }
}

// ---------------------------------------------------------------------------
// K4b: out[b][p] = sum_t mask[b][p][t] * (h[row_t] . W2 + b2)
// One block per (b,p); 4 waves x 16 tokens each; lane-strided dot over D.
// ---------------------------------------------------------------------------
__global__ __launch_bounds__(256) void score_reduce(
    const __hip_bfloat16* __restrict__ h, const float* __restrict__ mask,
    const float* __restrict__ W2, const float* __restrict__ b2,
    float* __restrict__ out)
{
    const int bp = blockIdx.x;  // 0..399
    const int b = bp / P_, p = bp % P_;
    const int lane = threadIdx.x & 63;
    const int w = threadIdx.x >> 6;

    float w2r[12];
#pragma unroll
    for (int i = 0; i < 12; ++i) w2r[i] = W2[lane + 64 * i];
    const float bias2 = b2[0];

    float acc = 0.0f;
    for (int t = w; t < TPP_; t += 4) {
        const __hip_bfloat16* row = h + ((size_t)b * T_ + (size_t)p * TPP_ + t) * D_;
        float s = 0.0f;
#pragma unroll
        for (int i = 0; i < 12; ++i)
            s += __bfloat162float(row[lane + 64 * i]) * w2r[i];
#pragma unroll
        for (int off = 32; off > 0; off >>= 1) s += __shfl_xor(s, off);
        if (lane == 0) acc += mask[(size_t)bp * TPP_ + t] * (s + bias2);
    }

    __shared__ float partial[4];
    if (lane == 0) partial[w] = acc;
    __syncthreads();
    if (threadIdx.x == 0)
        out[bp] = partial[0] + partial[1] + partial[2] + partial[3];
}

// ---------------------------------------------------------------------------
extern "C" void kernel_launch(void* const* d_in, const int* in_sizes, int n_in,
                              void* d_out, int out_size, void* d_ws, size_t ws_size,
                              hipStream_t stream)
{
    const float* answer = (const float*)d_in[0];
    const float* qps    = (const float*)d_in[1];
    const float* mask   = (const float*)d_in[2];
    const int*   tids   = (const int*)d_in[3];
    // d_in[4] = fusion_scores: unused by the reference
    const float* W_p = (const float*)d_in[5];
    const float* b_p = (const float*)d_in[6];
    const float* W_t = (const float*)d_in[7];
    const float* b_t = (const float*)d_in[8];
    const float* W1  = (const float*)d_in[9];
    const float* b1  = (const float*)d_in[10];
    const float* W2  = (const float*)d_in[11];
    const float* b2  = (const float*)d_in[12];
    float* out = (float*)d_out;

    char* ws = (char*)d_ws;
    float* Wp_eff = (float*)ws;             ws += (size_t)B_ * D_ * D_ * 4;   // 9.44 MB
    float* Wt_eff = (float*)ws;             ws += (size_t)B_ * D_ * D_ * 4;   // 9.44 MB
    float* c_p    = (float*)ws;             ws += (size_t)B_ * D_ * 4;
    float* c_t    = (float*)ws;             ws += (size_t)B_ * D_ * 4;
    __hip_bfloat16* ts = (__hip_bfloat16*)ws; ws += (size_t)B_ * T_ * D_ * 2; // 39.3 MB
    __hip_bfloat16* psb = (__hip_bfloat16*)ws; ws += (size_t)B_ * T_ * D_ * 2;// 39.3 MB
    __hip_bfloat16* sm = (__hip_bfloat16*)ws; ws += (size_t)B_ * G_ * TPP_ * D_ * 2; // 3.9 MB
    __hip_bfloat16* h  = ts;  // ts is dead after segmax; reuse for h

    prep_weights<<<(B_ * D_ * D_) / 256, 256, 0, stream>>>(answer, W_p, W_t, Wp_eff, Wt_eff);
    prep_const<<<(B_ * D_) / 256, 256, 0, stream>>>(answer, W_p, b_p, W_t, b_t, c_p, c_t);
    gemm_pt<<<dim3(T_ / 64, D_ / 64, B_), 256, 0, stream>>>(qps, Wp_eff, Wt_eff, c_p, c_t, psb, ts);
    segmax_kernel<<<(B_ * TPP_ * D_) / 256, 256, 0, stream>>>(ts, tids, sm);
    gemm_h<<<dim3(B_ * P_, D_ / 64), 256, 0, stream>>>(psb, sm, tids, W1, b1, h);
    score_reduce<<<B_ * P_, 256, 0, stream>>>(h, mask, W2, b2, out);
}

// Round 2
// 395.374 us; speedup vs baseline: 4.4057x; 4.4057x over previous
//
#include <hip/hip_runtime.h>
#include <hip/hip_bf16.h>

#define B_ 4
#define L_ 2
#define P_ 100
#define TPP_ 64
#define D_ 768
#define G_ 10
#define T_ (P_ * TPP_)   // 6400
#define NC_ (2 * D_)     // 1536 combined N for ps|ts GEMM

typedef __attribute__((ext_vector_type(8))) short bf16x8;
typedef __attribute__((ext_vector_type(4))) float f32x4;

__device__ __forceinline__ unsigned short f2bf(float f) {
    __hip_bfloat16 h = __float2bfloat16(f);
    return *reinterpret_cast<unsigned short*>(&h);
}

__device__ __forceinline__ void gload_lds16(const void* g, void* l) {
    __builtin_amdgcn_global_load_lds(
        (const __attribute__((address_space(1))) void*)g,
        (__attribute__((address_space(3))) void*)l, 16, 0, 0);
}

// ---------------------------------------------------------------------------
// P1: combined transposed effective weights (bf16, n-major):
//     Wct[b][n][k] = W[(D+k)*D + n'] + a[b][k] * W[(2D+k)*D + n']
//     n<768 -> W_p col n ; n>=768 -> W_t col n-768
// ---------------------------------------------------------------------------
__global__ __launch_bounds__(256) void prep_wct(
    const float* __restrict__ answer, const float* __restrict__ W_p,
    const float* __restrict__ W_t, __hip_bfloat16* __restrict__ Wct)
{
    size_t idx = (size_t)blockIdx.x * 256 + threadIdx.x;   // < B*1536*768 exact
    int k = (int)(idx % D_);
    int n = (int)((idx / D_) % NC_);
    int b = (int)(idx / ((size_t)D_ * NC_));
    const float* W = (n < D_) ? W_p : W_t;
    int nn = n & (D_ - 1);   // D_=768 not pow2! use modulo instead
    nn = (n < D_) ? n : n - D_;
    float a = answer[((size_t)b * L_ + (L_ - 1)) * D_ + k];
    float v = W[(size_t)(D_ + k) * D_ + nn] + a * W[(size_t)(2 * D_ + k) * D_ + nn];
    Wct[idx] = __float2bfloat16(v);
}

// ---------------------------------------------------------------------------
// P2: per-batch constants  c[b][d] = bias[d] + sum_k a[b][k] * W[k][d]
// ---------------------------------------------------------------------------
__global__ __launch_bounds__(256) void prep_const(
    const float* __restrict__ answer,
    const float* __restrict__ W_p, const float* __restrict__ b_p,
    const float* __restrict__ W_t, const float* __restrict__ b_t,
    float* __restrict__ c_p, float* __restrict__ c_t)
{
    int idx = blockIdx.x * 256 + threadIdx.x;  // < B*D exact
    int d = idx % D_;
    int b = idx / D_;
    const float* a = answer + ((size_t)b * L_ + (L_ - 1)) * D_;
    float sp = b_p[d], st = b_t[d];
    for (int k = 0; k < D_; ++k) {
        float av = a[k];
        sp += av * W_p[(size_t)k * D_ + d];
        st += av * W_t[(size_t)k * D_ + d];
    }
    c_p[idx] = sp;
    c_t[idx] = st;
}

// ---------------------------------------------------------------------------
// P3: q slice (L-1) fp32 -> bf16, vectorized 4/thread
// ---------------------------------------------------------------------------
__global__ __launch_bounds__(256) void conv_q(
    const float* __restrict__ q, __hip_bfloat16* __restrict__ qb)
{
    size_t base = ((size_t)blockIdx.x * 256 + threadIdx.x) * 4;  // < B*T*D exact
    int b = (int)(base / ((size_t)T_ * D_));
    size_t off = base % ((size_t)T_ * D_);
    float4 v = *reinterpret_cast<const float4*>(
        &q[((size_t)b * L_ + (L_ - 1)) * (size_t)T_ * D_ + off]);
    ushort4 o;
    o.x = f2bf(v.x); o.y = f2bf(v.y); o.z = f2bf(v.z); o.w = f2bf(v.w);
    *reinterpret_cast<ushort4*>(&qb[base]) = o;
}

// ---------------------------------------------------------------------------
// P4: W1 transposed to bf16:  W1t[n][k] = W1[k*768 + n]
// ---------------------------------------------------------------------------
__global__ __launch_bounds__(256) void prep_w1t(
    const float* __restrict__ W1, __hip_bfloat16* __restrict__ W1t)
{
    int idx = blockIdx.x * 256 + threadIdx.x;   // < 768*1536 exact
    int k = idx % NC_;
    int n = idx / NC_;
    W1t[idx] = __float2bfloat16(W1[(size_t)k * D_ + n]);
}

// ---------------------------------------------------------------------------
// K2: MFMA GEMM  [ps|ts] = qb @ Wct[b]^T + [c_p|c_t]
//     per batch M=6400, N=1536, K=768. 128x128 tile, BK=32, 4 waves 2x2.
// ---------------------------------------------------------------------------
__global__ __launch_bounds__(256) void gemm_pt_mfma(
    const __hip_bfloat16* __restrict__ qb,   // [B][T][768]
    const __hip_bfloat16* __restrict__ Wct,  // [B][1536][768] n-major
    const float* __restrict__ c_p, const float* __restrict__ c_t,
    __hip_bfloat16* __restrict__ ps, __hip_bfloat16* __restrict__ ts)
{
    const int tm = blockIdx.x;      // 0..49
    const int tn = blockIdx.y;      // 0..11
    const int b  = blockIdx.z;

    __shared__ __align__(16) __hip_bfloat16 As[128][32];  // 8KB, m-major
    __shared__ __align__(16) __hip_bfloat16 Bs[128][32];  // 8KB, n-major

    const int tid = threadIdx.x;
    const int lane = tid & 63;
    const int w = tid >> 6;
    const int wm = w & 1, wn = w >> 1;

    const __hip_bfloat16* Ab = qb + (size_t)b * T_ * D_ + (size_t)tm * 128 * D_;
    const __hip_bfloat16* Bb = Wct + (size_t)b * NC_ * D_ + (size_t)tn * 128 * D_;

    f32x4 acc[4][4];
#pragma unroll
    for (int i = 0; i < 4; ++i)
#pragma unroll
        for (int j = 0; j < 4; ++j)
#pragma unroll
            for (int e = 0; e < 4; ++e) acc[i][j][e] = 0.0f;

    const int srow = lane >> 2;          // 0..15 within chunk
    const int scol = (lane & 3) * 8;     // bf16 offset within row

    for (int k0 = 0; k0 < D_; k0 += 32) {
#pragma unroll
        for (int i = 0; i < 2; ++i) {
            int c = w * 2 + i;           // chunk 0..7 (16 rows each)
            gload_lds16(Ab + (size_t)(c * 16 + srow) * D_ + k0 + scol, &As[c * 16][0]);
            gload_lds16(Bb + (size_t)(c * 16 + srow) * D_ + k0 + scol, &Bs[c * 16][0]);
        }
        __syncthreads();

        bf16x8 af[4], bfr[4];
#pragma unroll
        for (int mi = 0; mi < 4; ++mi)
            af[mi] = *reinterpret_cast<const bf16x8*>(
                &As[wm * 64 + mi * 16 + (lane & 15)][(lane >> 4) * 8]);
#pragma unroll
        for (int ni = 0; ni < 4; ++ni)
            bfr[ni] = *reinterpret_cast<const bf16x8*>(
                &Bs[wn * 64 + ni * 16 + (lane & 15)][(lane >> 4) * 8]);
#pragma unroll
        for (int mi = 0; mi < 4; ++mi)
#pragma unroll
            for (int ni = 0; ni < 4; ++ni)
                acc[mi][ni] = __builtin_amdgcn_mfma_f32_16x16x32_bf16(
                    af[mi], bfr[ni], acc[mi][ni], 0, 0, 0);
        __syncthreads();
    }

#pragma unroll
    for (int mi = 0; mi < 4; ++mi)
#pragma unroll
        for (int ni = 0; ni < 4; ++ni) {
            int col = tn * 128 + wn * 64 + ni * 16 + (lane & 15);
            int rb  = tm * 128 + wm * 64 + mi * 16 + (lane >> 4) * 4;
#pragma unroll
            for (int e = 0; e < 4; ++e) {
                int r = rb + e;
                float v = acc[mi][ni][e];
                if (col < D_)
                    ps[((size_t)b * T_ + r) * D_ + col] =
                        __float2bfloat16(v + c_p[b * D_ + col]);
                else
                    ts[((size_t)b * T_ + r) * D_ + col - D_] =
                        __float2bfloat16(v + c_t[b * D_ + col - D_]);
            }
        }
}

// ---------------------------------------------------------------------------
// K3: segment max. sm[b][g][t][d] = max_{p: tid==g} ts[b][p*64+t][d]
// ---------------------------------------------------------------------------
__global__ __launch_bounds__(256) void segmax_kernel(
    const __hip_bfloat16* __restrict__ ts, const int* __restrict__ table_ids,
    __hip_bfloat16* __restrict__ sm)
{
    int idx = blockIdx.x * 256 + threadIdx.x;  // < B*TPP*D exact
    int d = idx % D_;
    int bt = idx / D_;
    int t = bt % TPP_;
    int b = bt / TPP_;

    float m[G_];
#pragma unroll
    for (int g = 0; g < G_; ++g) m[g] = -1e30f;

    const __hip_bfloat16* base = ts + ((size_t)b * T_ + t) * D_ + d;
    for (int p = 0; p < P_; ++p) {
        int g = table_ids[b * P_ + p];
        float v = __bfloat162float(base[(size_t)p * TPP_ * D_]);
#pragma unroll
        for (int gg = 0; gg < G_; ++gg)
            m[gg] = (gg == g) ? fmaxf(m[gg], v) : m[gg];
    }
#pragma unroll
    for (int g = 0; g < G_; ++g)
        sm[(((size_t)b * G_ + g) * TPP_ + t) * D_ + d] = __float2bfloat16(m[g]);
}

// ---------------------------------------------------------------------------
// K4: MFMA GEMM  h = relu([ps | sm[tid[p]]] @ W1t^T + b1)
//     M=6400 (per batch), N=768, K=1536. Same structure as K2; the A-concat
//     is folded into the per-lane global_load_lds source address.
// ---------------------------------------------------------------------------
__global__ __launch_bounds__(256) void gemm_h_mfma(
    const __hip_bfloat16* __restrict__ ps, const __hip_bfloat16* __restrict__ sm,
    const int* __restrict__ tids, const __hip_bfloat16* __restrict__ W1t,
    const float* __restrict__ b1, __hip_bfloat16* __restrict__ h)
{
    const int tm = blockIdx.x;      // 0..49
    const int tn = blockIdx.y;      // 0..5
    const int b  = blockIdx.z;

    __shared__ __align__(16) __hip_bfloat16 As[128][32];
    __shared__ __align__(16) __hip_bfloat16 Bs[128][32];

    const int tid = threadIdx.x;
    const int lane = tid & 63;
    const int w = tid >> 6;
    const int wm = w & 1, wn = w >> 1;

    f32x4 acc[4][4];
#pragma unroll
    for (int i = 0; i < 4; ++i)
#pragma unroll
        for (int j = 0; j < 4; ++j)
#pragma unroll
            for (int e = 0; e < 4; ++e) acc[i][j][e] = 0.0f;

    const int srow = lane >> 2;
    const int scol = (lane & 3) * 8;

    for (int k0 = 0; k0 < 2 * D_; k0 += 32) {
#pragma unroll
        for (int i = 0; i < 2; ++i) {
            int c = w * 2 + i;
            int m = tm * 128 + c * 16 + srow;
            const __hip_bfloat16* asrc;
            if (k0 < D_) {
                asrc = ps + ((size_t)b * T_ + m) * D_ + k0 + scol;
            } else {
                int p = m >> 6, t = m & 63;
                int g = tids[b * P_ + p];
                asrc = sm + (((size_t)b * G_ + g) * TPP_ + t) * D_ + (k0 - D_) + scol;
            }
            gload_lds16(asrc, &As[c * 16][0]);
            gload_lds16(W1t + (size_t)(tn * 128 + c * 16 + srow) * NC_ + k0 + scol,
                        &Bs[c * 16][0]);
        }
        __syncthreads();

        bf16x8 af[4], bfr[4];
#pragma unroll
        for (int mi = 0; mi < 4; ++mi)
            af[mi] = *reinterpret_cast<const bf16x8*>(
                &As[wm * 64 + mi * 16 + (lane & 15)][(lane >> 4) * 8]);
#pragma unroll
        for (int ni = 0; ni < 4; ++ni)
            bfr[ni] = *reinterpret_cast<const bf16x8*>(
                &Bs[wn * 64 + ni * 16 + (lane & 15)][(lane >> 4) * 8]);
#pragma unroll
        for (int mi = 0; mi < 4; ++mi)
#pragma unroll
            for (int ni = 0; ni < 4; ++ni)
                acc[mi][ni] = __builtin_amdgcn_mfma_f32_16x16x32_bf16(
                    af[mi], bfr[ni], acc[mi][ni], 0, 0, 0);
        __syncthreads();
    }

#pragma unroll
    for (int mi = 0; mi < 4; ++mi)
#pragma unroll
        for (int ni = 0; ni < 4; ++ni) {
            int col = tn * 128 + wn * 64 + ni * 16 + (lane & 15);
            int rb  = tm * 128 + wm * 64 + mi * 16 + (lane >> 4) * 4;
#pragma unroll
            for (int e = 0; e < 4; ++e) {
                int r = rb + e;
                float v = acc[mi][ni][e] + b1[col];
                h[((size_t)b * T_ + r) * D_ + col] = __float2bfloat16(fmaxf(v, 0.0f));
            }
        }
}

// ---------------------------------------------------------------------------
// K5: out[b][p] = sum_t mask[b][p][t] * (h[row_t] . W2 + b2)
// ---------------------------------------------------------------------------
__global__ __launch_bounds__(256) void score_reduce(
    const __hip_bfloat16* __restrict__ h, const float* __restrict__ mask,
    const float* __restrict__ W2, const float* __restrict__ b2,
    float* __restrict__ out)
{
    const int bp = blockIdx.x;  // 0..399
    const int b = bp / P_, p = bp % P_;
    const int lane = threadIdx.x & 63;
    const int w = threadIdx.x >> 6;

    float w2r[12];
#pragma unroll
    for (int i = 0; i < 12; ++i) w2r[i] = W2[lane + 64 * i];
    const float bias2 = b2[0];

    float acc = 0.0f;
    for (int t = w; t < TPP_; t += 4) {
        const __hip_bfloat16* row = h + ((size_t)b * T_ + (size_t)p * TPP_ + t) * D_;
        float s = 0.0f;
#pragma unroll
        for (int i = 0; i < 12; ++i)
            s += __bfloat162float(row[lane + 64 * i]) * w2r[i];
#pragma unroll
        for (int off = 32; off > 0; off >>= 1) s += __shfl_xor(s, off);
        if (lane == 0) acc += mask[(size_t)bp * TPP_ + t] * (s + bias2);
    }

    __shared__ float partial[4];
    if (lane == 0) partial[w] = acc;
    __syncthreads();
    if (threadIdx.x == 0)
        out[bp] = partial[0] + partial[1] + partial[2] + partial[3];
}

// ---------------------------------------------------------------------------
extern "C" void kernel_launch(void* const* d_in, const int* in_sizes, int n_in,
                              void* d_out, int out_size, void* d_ws, size_t ws_size,
                              hipStream_t stream)
{
    const float* answer = (const float*)d_in[0];
    const float* qps    = (const float*)d_in[1];
    const float* mask   = (const float*)d_in[2];
    const int*   tids   = (const int*)d_in[3];
    // d_in[4] = fusion_scores: unused by the reference
    const float* W_p = (const float*)d_in[5];
    const float* b_p = (const float*)d_in[6];
    const float* W_t = (const float*)d_in[7];
    const float* b_t = (const float*)d_in[8];
    const float* W1  = (const float*)d_in[9];
    const float* b1  = (const float*)d_in[10];
    const float* W2  = (const float*)d_in[11];
    const float* b2  = (const float*)d_in[12];
    float* out = (float*)d_out;

    char* ws = (char*)d_ws;
    __hip_bfloat16* Wct = (__hip_bfloat16*)ws; ws += (size_t)B_ * NC_ * D_ * 2;  // 9.44 MB
    float* c_p = (float*)ws;                   ws += (size_t)B_ * D_ * 4;
    float* c_t = (float*)ws;                   ws += (size_t)B_ * D_ * 4;
    __hip_bfloat16* qb = (__hip_bfloat16*)ws;  ws += (size_t)B_ * T_ * D_ * 2;   // 39.3 MB
    __hip_bfloat16* ps = (__hip_bfloat16*)ws;  ws += (size_t)B_ * T_ * D_ * 2;   // 39.3 MB
    __hip_bfloat16* ts = (__hip_bfloat16*)ws;  ws += (size_t)B_ * T_ * D_ * 2;   // 39.3 MB
    __hip_bfloat16* sm = (__hip_bfloat16*)ws;  ws += (size_t)B_ * G_ * TPP_ * D_ * 2; // 3.9 MB
    __hip_bfloat16* W1t = (__hip_bfloat16*)ws; ws += (size_t)D_ * NC_ * 2;       // 2.36 MB
    __hip_bfloat16* h = qb;  // qb dead after gemm_pt_mfma

    prep_wct<<<(B_ * NC_ * D_) / 256, 256, 0, stream>>>(answer, W_p, W_t, Wct);
    prep_const<<<(B_ * D_) / 256, 256, 0, stream>>>(answer, W_p, b_p, W_t, b_t, c_p, c_t);
    conv_q<<<(B_ * T_ * D_) / (256 * 4), 256, 0, stream>>>(qps, qb);
    prep_w1t<<<(D_ * NC_) / 256, 256, 0, stream>>>(W1, W1t);
    gemm_pt_mfma<<<dim3(T_ / 128, NC_ / 128, B_), 256, 0, stream>>>(
        qb, Wct, c_p, c_t, ps, ts);
    segmax_kernel<<<(B_ * TPP_ * D_) / 256, 256, 0, stream>>>(ts, tids, sm);
    gemm_h_mfma<<<dim3(T_ / 128, D_ / 128, B_), 256, 0, stream>>>(
        ps, sm, tids, W1t, b1, h);
    score_reduce<<<B_ * P_, 256, 0, stream>>>(h, mask, W2, b2, out);
}

// Round 3
// 293.297 us; speedup vs baseline: 5.9390x; 1.3480x over previous
//
#include <hip/hip_runtime.h>
#include <hip/hip_bf16.h>

#define B_ 4
#define L_ 2
#define P_ 100
#define TPP_ 64
#define D_ 768
#define G_ 10
#define T_ (P_ * TPP_)   // 6400
#define NC_ (2 * D_)     // 1536

typedef __attribute__((ext_vector_type(8))) short bf16x8;
typedef __attribute__((ext_vector_type(4))) float f32x4;

__device__ __forceinline__ unsigned short f2bf(float f) {
    __hip_bfloat16 h = __float2bfloat16(f);
    return *reinterpret_cast<unsigned short*>(&h);
}

__device__ __forceinline__ void gload_lds16(const void* g, void* l) {
    __builtin_amdgcn_global_load_lds(
        (const __attribute__((address_space(1))) void*)g,
        (__attribute__((address_space(3))) void*)l, 16, 0, 0);
}

// Latin-square slot swizzle within each 16-row x 64B staged chunk:
// LDS(r, sl) holds global (r, sl ^ m(r)), m(r) = (r&3)^((r>>2)&3).
// Writer: gload_lds dest is linear (lane*16B); pre-swizzle the GLOBAL source.
// Reader: XOR its slot with m(row%16). 8-way bank conflict -> 2-way (free).
__device__ __forceinline__ int swz_m(int r) { return (r & 3) ^ ((r >> 2) & 3); }

// ---------------------------------------------------------------------------
// P1: Wct[b][n][k] = W[(D+k)*D+n'] + a[b][k]*W[(2D+k)*D+n']  (bf16, n-major)
//     n<768 -> W_p, else W_t.  LDS-transposed for coalescing both sides.
//     grid (NC/64, D/64, B), 256 thr.
// ---------------------------------------------------------------------------
__global__ __launch_bounds__(256) void prep_wct(
    const float* __restrict__ answer, const float* __restrict__ W_p,
    const float* __restrict__ W_t, __hip_bfloat16* __restrict__ Wct)
{
    __shared__ float lds[64][65];
    __shared__ float a_s[64];
    const int n0 = blockIdx.x * 64;       // 0..1535
    const int k0 = blockIdx.y * 64;       // 0..767
    const int b  = blockIdx.z;
    const int tid = threadIdx.x;

    if (tid < 64) a_s[tid] = answer[((size_t)b * L_ + (L_ - 1)) * D_ + k0 + tid];
    __syncthreads();

    const float* W = (n0 < D_) ? W_p : W_t;
    const int nn0 = (n0 < D_) ? n0 : n0 - D_;
#pragma unroll
    for (int i = 0; i < 16; ++i) {
        int k = (tid >> 6) + i * 4;
        int n = tid & 63;
        float w1v = W[(size_t)(D_ + k0 + k) * D_ + nn0 + n];
        float w2v = W[(size_t)(2 * D_ + k0 + k) * D_ + nn0 + n];
        lds[k][n] = w1v + a_s[k] * w2v;
    }
    __syncthreads();
#pragma unroll
    for (int j = 0; j < 16; ++j) {
        int n = (tid >> 6) + j * 4;
        int kk = tid & 63;
        Wct[((size_t)b * NC_ + n0 + n) * D_ + k0 + kk] = __float2bfloat16(lds[kk][n]);
    }
}

// ---------------------------------------------------------------------------
// P2: c[b][d] = bias[d] + sum_k a[b][k]*W[k][d].  grid (B, D/64), 512 thr.
// ---------------------------------------------------------------------------
__global__ __launch_bounds__(512) void prep_const(
    const float* __restrict__ answer,
    const float* __restrict__ W_p, const float* __restrict__ b_p,
    const float* __restrict__ W_t, const float* __restrict__ b_t,
    float* __restrict__ c_p, float* __restrict__ c_t)
{
    const int b = blockIdx.x;
    const int d = blockIdx.y * 64 + (threadIdx.x & 63);
    const int ks = threadIdx.x >> 6;   // 0..7
    const float* a = answer + ((size_t)b * L_ + (L_ - 1)) * D_;
    float sp = 0.f, st = 0.f;
    for (int k = ks; k < D_; k += 8) {
        float av = a[k];
        sp += av * W_p[(size_t)k * D_ + d];
        st += av * W_t[(size_t)k * D_ + d];
    }
    __shared__ float red[2][8][64];
    red[0][ks][threadIdx.x & 63] = sp;
    red[1][ks][threadIdx.x & 63] = st;
    __syncthreads();
    if (ks == 0) {
        float s1 = b_p[d], s2 = b_t[d];
#pragma unroll
        for (int i = 0; i < 8; ++i) {
            s1 += red[0][i][threadIdx.x & 63];
            s2 += red[1][i][threadIdx.x & 63];
        }
        c_p[b * D_ + d] = s1;
        c_t[b * D_ + d] = s2;
    }
}

// ---------------------------------------------------------------------------
// P3: q slice (L-1) fp32 -> bf16
// ---------------------------------------------------------------------------
__global__ __launch_bounds__(256) void conv_q(
    const float* __restrict__ q, __hip_bfloat16* __restrict__ qb)
{
    size_t base = ((size_t)blockIdx.x * 256 + threadIdx.x) * 4;
    int b = (int)(base / ((size_t)T_ * D_));
    size_t off = base % ((size_t)T_ * D_);
    float4 v = *reinterpret_cast<const float4*>(
        &q[((size_t)b * L_ + (L_ - 1)) * (size_t)T_ * D_ + off]);
    ushort4 o;
    o.x = f2bf(v.x); o.y = f2bf(v.y); o.z = f2bf(v.z); o.w = f2bf(v.w);
    *reinterpret_cast<ushort4*>(&qb[base]) = o;
}

// ---------------------------------------------------------------------------
// P4: W1 (1536x768 fp32) -> W1at[n][k]=W1[k][n] (k<768), W1bt[n][k]=W1[768+k][n]
//     grid (D/64, NC/64), 256 thr, LDS transpose.
// ---------------------------------------------------------------------------
__global__ __launch_bounds__(256) void prep_w1t(
    const float* __restrict__ W1, __hip_bfloat16* __restrict__ W1at,
    __hip_bfloat16* __restrict__ W1bt)
{
    __shared__ float lds[64][65];
    const int n0 = blockIdx.x * 64;   // 0..767
    const int k0 = blockIdx.y * 64;   // 0..1535
    const int tid = threadIdx.x;
#pragma unroll
    for (int i = 0; i < 16; ++i) {
        int k = (tid >> 6) + i * 4;
        int n = tid & 63;
        lds[k][n] = W1[(size_t)(k0 + k) * D_ + n0 + n];
    }
    __syncthreads();
    __hip_bfloat16* dst = (k0 < D_) ? W1at : W1bt;
    const int kk0 = (k0 < D_) ? k0 : k0 - D_;
#pragma unroll
    for (int j = 0; j < 16; ++j) {
        int n = (tid >> 6) + j * 4;
        int kk = tid & 63;
        dst[(size_t)(n0 + n) * D_ + kk0 + kk] = __float2bfloat16(lds[kk][n]);
    }
}

// ---------------------------------------------------------------------------
// K2: [ps|ts] = qb @ Wct[b]^T + [c_p|c_t].  128x128 tile, BK=32, swizzled LDS.
// ---------------------------------------------------------------------------
__global__ __launch_bounds__(256) void gemm_pt_mfma(
    const __hip_bfloat16* __restrict__ qb,
    const __hip_bfloat16* __restrict__ Wct,
    const float* __restrict__ c_p, const float* __restrict__ c_t,
    __hip_bfloat16* __restrict__ ps, __hip_bfloat16* __restrict__ ts)
{
    const int tm = blockIdx.x, tn = blockIdx.y, b = blockIdx.z;

    __shared__ __align__(16) __hip_bfloat16 As[128][32];
    __shared__ __align__(16) __hip_bfloat16 Bs[128][32];

    const int tid = threadIdx.x;
    const int lane = tid & 63;
    const int w = tid >> 6;
    const int wm = w & 1, wn = w >> 1;

    const __hip_bfloat16* Ab = qb + (size_t)b * T_ * D_ + (size_t)tm * 128 * D_;
    const __hip_bfloat16* Bb = Wct + (size_t)b * NC_ * D_ + (size_t)tn * 128 * D_;

    f32x4 acc[4][4];
#pragma unroll
    for (int i = 0; i < 4; ++i)
#pragma unroll
        for (int j = 0; j < 4; ++j)
#pragma unroll
            for (int e = 0; e < 4; ++e) acc[i][j][e] = 0.0f;

    const int srow = lane >> 2;
    const int scol = ((lane & 3) ^ swz_m(srow)) * 8;   // pre-swizzled source
    const int rr = lane & 15;
    const int rslot = ((lane >> 4) ^ swz_m(rr)) * 8;   // swizzled read

    for (int k0 = 0; k0 < D_; k0 += 32) {
#pragma unroll
        for (int i = 0; i < 2; ++i) {
            int c = w * 2 + i;
            gload_lds16(Ab + (size_t)(c * 16 + srow) * D_ + k0 + scol, &As[c * 16][0]);
            gload_lds16(Bb + (size_t)(c * 16 + srow) * D_ + k0 + scol, &Bs[c * 16][0]);
        }
        __syncthreads();

        bf16x8 af[4], bfr[4];
#pragma unroll
        for (int mi = 0; mi < 4; ++mi)
            af[mi] = *reinterpret_cast<const bf16x8*>(&As[wm * 64 + mi * 16 + rr][rslot]);
#pragma unroll
        for (int ni = 0; ni < 4; ++ni)
            bfr[ni] = *reinterpret_cast<const bf16x8*>(&Bs[wn * 64 + ni * 16 + rr][rslot]);
#pragma unroll
        for (int mi = 0; mi < 4; ++mi)
#pragma unroll
            for (int ni = 0; ni < 4; ++ni)
                acc[mi][ni] = __builtin_amdgcn_mfma_f32_16x16x32_bf16(
                    af[mi], bfr[ni], acc[mi][ni], 0, 0, 0);
        __syncthreads();
    }

#pragma unroll
    for (int mi = 0; mi < 4; ++mi)
#pragma unroll
        for (int ni = 0; ni < 4; ++ni) {
            int col = tn * 128 + wn * 64 + ni * 16 + (lane & 15);
            int rb  = tm * 128 + wm * 64 + mi * 16 + (lane >> 4) * 4;
#pragma unroll
            for (int e = 0; e < 4; ++e) {
                int r = rb + e;
                float v = acc[mi][ni][e];
                if (col < D_)
                    ps[((size_t)b * T_ + r) * D_ + col] =
                        __float2bfloat16(v + c_p[b * D_ + col]);
                else
                    ts[((size_t)b * T_ + r) * D_ + col - D_] =
                        __float2bfloat16(v + c_t[b * D_ + col - D_]);
            }
        }
}

// ---------------------------------------------------------------------------
// K3: sm[b][g][t][d] = max_{p: tids==g} ts[b][p*64+t][d]
// ---------------------------------------------------------------------------
__global__ __launch_bounds__(256) void segmax_kernel(
    const __hip_bfloat16* __restrict__ ts, const int* __restrict__ table_ids,
    __hip_bfloat16* __restrict__ sm)
{
    int idx = blockIdx.x * 256 + threadIdx.x;
    int d = idx % D_;
    int bt = idx / D_;
    int t = bt % TPP_;
    int b = bt / TPP_;

    float m[G_];
#pragma unroll
    for (int g = 0; g < G_; ++g) m[g] = -1e30f;

    const __hip_bfloat16* base = ts + ((size_t)b * T_ + t) * D_ + d;
    for (int p = 0; p < P_; ++p) {
        int g = table_ids[b * P_ + p];
        float v = __bfloat162float(base[(size_t)p * TPP_ * D_]);
#pragma unroll
        for (int gg = 0; gg < G_; ++gg)
            m[gg] = (gg == g) ? fmaxf(m[gg], v) : m[gg];
    }
#pragma unroll
    for (int g = 0; g < G_; ++g)
        sm[(((size_t)b * G_ + g) * TPP_ + t) * D_ + d] = __float2bfloat16(m[g]);
}

// ---------------------------------------------------------------------------
// K3b: smW = sm @ W1bt^T   (M=2560, N=768, K=768), plain bf16 out.
// ---------------------------------------------------------------------------
__global__ __launch_bounds__(256) void gemm_smw(
    const __hip_bfloat16* __restrict__ sm, const __hip_bfloat16* __restrict__ W1bt,
    __hip_bfloat16* __restrict__ smW)
{
    const int tm = blockIdx.x, tn = blockIdx.y;

    __shared__ __align__(16) __hip_bfloat16 As[128][32];
    __shared__ __align__(16) __hip_bfloat16 Bs[128][32];

    const int tid = threadIdx.x;
    const int lane = tid & 63;
    const int w = tid >> 6;
    const int wm = w & 1, wn = w >> 1;

    const __hip_bfloat16* Ab = sm + (size_t)tm * 128 * D_;
    const __hip_bfloat16* Bb = W1bt + (size_t)tn * 128 * D_;

    f32x4 acc[4][4];
#pragma unroll
    for (int i = 0; i < 4; ++i)
#pragma unroll
        for (int j = 0; j < 4; ++j)
#pragma unroll
            for (int e = 0; e < 4; ++e) acc[i][j][e] = 0.0f;

    const int srow = lane >> 2;
    const int scol = ((lane & 3) ^ swz_m(srow)) * 8;
    const int rr = lane & 15;
    const int rslot = ((lane >> 4) ^ swz_m(rr)) * 8;

    for (int k0 = 0; k0 < D_; k0 += 32) {
#pragma unroll
        for (int i = 0; i < 2; ++i) {
            int c = w * 2 + i;
            gload_lds16(Ab + (size_t)(c * 16 + srow) * D_ + k0 + scol, &As[c * 16][0]);
            gload_lds16(Bb + (size_t)(c * 16 + srow) * D_ + k0 + scol, &Bs[c * 16][0]);
        }
        __syncthreads();

        bf16x8 af[4], bfr[4];
#pragma unroll
        for (int mi = 0; mi < 4; ++mi)
            af[mi] = *reinterpret_cast<const bf16x8*>(&As[wm * 64 + mi * 16 + rr][rslot]);
#pragma unroll
        for (int ni = 0; ni < 4; ++ni)
            bfr[ni] = *reinterpret_cast<const bf16x8*>(&Bs[wn * 64 + ni * 16 + rr][rslot]);
#pragma unroll
        for (int mi = 0; mi < 4; ++mi)
#pragma unroll
            for (int ni = 0; ni < 4; ++ni)
                acc[mi][ni] = __builtin_amdgcn_mfma_f32_16x16x32_bf16(
                    af[mi], bfr[ni], acc[mi][ni], 0, 0, 0);
        __syncthreads();
    }

#pragma unroll
    for (int mi = 0; mi < 4; ++mi)
#pragma unroll
        for (int ni = 0; ni < 4; ++ni) {
            int col = tn * 128 + wn * 64 + ni * 16 + (lane & 15);
            int rb  = tm * 128 + wm * 64 + mi * 16 + (lane >> 4) * 4;
#pragma unroll
            for (int e = 0; e < 4; ++e)
                smW[(size_t)(rb + e) * D_ + col] = __float2bfloat16(acc[mi][ni][e]);
        }
}

// ---------------------------------------------------------------------------
// K4a: out[bp] = b2 * sum_t mask[bp][t]   (atomicAdd base term)
// ---------------------------------------------------------------------------
__global__ __launch_bounds__(256) void out_init(
    const float* __restrict__ mask, const float* __restrict__ b2,
    float* __restrict__ out)
{
    int bp = blockIdx.x * 256 + threadIdx.x;
    if (bp >= B_ * P_) return;
    float s = 0.f;
#pragma unroll 8
    for (int t = 0; t < TPP_; ++t) s += mask[(size_t)bp * TPP_ + t];
    out[bp] = s * b2[0];
}

// ---------------------------------------------------------------------------
// K4: fused  acc = ps @ W1at^T ;  v = relu(acc + b1 + smW[g(p)])
//     rowdot = v . W2 ;  out[b][p] += sum_t mask * rowdot
//     M=6400/batch, N=768, K=768.  h never materializes.
// ---------------------------------------------------------------------------
__global__ __launch_bounds__(256) void gemm_h_fused(
    const __hip_bfloat16* __restrict__ ps, const __hip_bfloat16* __restrict__ smW,
    const int* __restrict__ tids, const __hip_bfloat16* __restrict__ W1at,
    const float* __restrict__ b1, const float* __restrict__ W2,
    const float* __restrict__ mask, float* __restrict__ out)
{
    const int tm = blockIdx.x, tn = blockIdx.y, b = blockIdx.z;

    __shared__ __align__(16) __hip_bfloat16 As[128][32];
    __shared__ __align__(16) __hip_bfloat16 Bs[128][32];
    __shared__ float rowsum[2][128];

    const int tid = threadIdx.x;
    const int lane = tid & 63;
    const int w = tid >> 6;
    const int wm = w & 1, wn = w >> 1;

    const __hip_bfloat16* Ab = ps + (size_t)b * T_ * D_ + (size_t)tm * 128 * D_;
    const __hip_bfloat16* Bb = W1at + (size_t)tn * 128 * D_;

    f32x4 acc[4][4];
#pragma unroll
    for (int i = 0; i < 4; ++i)
#pragma unroll
        for (int j = 0; j < 4; ++j)
#pragma unroll
            for (int e = 0; e < 4; ++e) acc[i][j][e] = 0.0f;

    const int srow = lane >> 2;
    const int scol = ((lane & 3) ^ swz_m(srow)) * 8;
    const int rr = lane & 15;
    const int rslot = ((lane >> 4) ^ swz_m(rr)) * 8;

    for (int k0 = 0; k0 < D_; k0 += 32) {
#pragma unroll
        for (int i = 0; i < 2; ++i) {
            int c = w * 2 + i;
            gload_lds16(Ab + (size_t)(c * 16 + srow) * D_ + k0 + scol, &As[c * 16][0]);
            gload_lds16(Bb + (size_t)(c * 16 + srow) * D_ + k0 + scol, &Bs[c * 16][0]);
        }
        __syncthreads();

        bf16x8 af[4], bfr[4];
#pragma unroll
        for (int mi = 0; mi < 4; ++mi)
            af[mi] = *reinterpret_cast<const bf16x8*>(&As[wm * 64 + mi * 16 + rr][rslot]);
#pragma unroll
        for (int ni = 0; ni < 4; ++ni)
            bfr[ni] = *reinterpret_cast<const bf16x8*>(&Bs[wn * 64 + ni * 16 + rr][rslot]);
#pragma unroll
        for (int mi = 0; mi < 4; ++mi)
#pragma unroll
            for (int ni = 0; ni < 4; ++ni)
                acc[mi][ni] = __builtin_amdgcn_mfma_f32_16x16x32_bf16(
                    af[mi], bfr[ni], acc[mi][ni], 0, 0, 0);
        __syncthreads();
    }

    // ---- fused epilogue: relu(acc + b1 + smW) . W2, reduce, atomicAdd ----
    const int p = tm * 2 + wm;              // this wave's passage
    const int g = tids[b * P_ + p];
    const __hip_bfloat16* smWg = smW + ((size_t)(b * G_ + g) * TPP_) * D_;

    float rs[4][4];                          // [mi][e] row partial dots
#pragma unroll
    for (int mi = 0; mi < 4; ++mi)
#pragma unroll
        for (int e = 0; e < 4; ++e) rs[mi][e] = 0.f;

#pragma unroll
    for (int ni = 0; ni < 4; ++ni) {
        int col = tn * 128 + wn * 64 + ni * 16 + (lane & 15);
        float b1v = b1[col];
        float w2v = W2[col];
#pragma unroll
        for (int mi = 0; mi < 4; ++mi)
#pragma unroll
            for (int e = 0; e < 4; ++e) {
                int trow = mi * 16 + (lane >> 4) * 4 + e;
                float v = acc[mi][ni][e] + b1v +
                          __bfloat162float(smWg[(size_t)trow * D_ + col]);
                rs[mi][e] += fmaxf(v, 0.f) * w2v;
            }
    }
    // reduce across the 16 col-lanes (same lane>>4 group => same rows)
#pragma unroll
    for (int off = 8; off >= 1; off >>= 1)
#pragma unroll
        for (int mi = 0; mi < 4; ++mi)
#pragma unroll
            for (int e = 0; e < 4; ++e) rs[mi][e] += __shfl_xor(rs[mi][e], off);

    if ((lane & 15) == 0) {
#pragma unroll
        for (int mi = 0; mi < 4; ++mi)
#pragma unroll
            for (int e = 0; e < 4; ++e)
                rowsum[wn][wm * 64 + mi * 16 + (lane >> 4) * 4 + e] = rs[mi][e];
    }
    __syncthreads();

    if (tid < 128) {
        int pp = tid >> 6, t = tid & 63;
        float v = (rowsum[0][tid] + rowsum[1][tid]) *
                  mask[((size_t)b * P_ + tm * 2 + pp) * TPP_ + t];
#pragma unroll
        for (int off = 32; off >= 1; off >>= 1) v += __shfl_xor(v, off);
        if (t == 0) atomicAdd(&out[b * P_ + tm * 2 + pp], v);
    }
}

// ---------------------------------------------------------------------------
extern "C" void kernel_launch(void* const* d_in, const int* in_sizes, int n_in,
                              void* d_out, int out_size, void* d_ws, size_t ws_size,
                              hipStream_t stream)
{
    const float* answer = (const float*)d_in[0];
    const float* qps    = (const float*)d_in[1];
    const float* mask   = (const float*)d_in[2];
    const int*   tids   = (const int*)d_in[3];
    // d_in[4] = fusion_scores: unused by the reference
    const float* W_p = (const float*)d_in[5];
    const float* b_p = (const float*)d_in[6];
    const float* W_t = (const float*)d_in[7];
    const float* b_t = (const float*)d_in[8];
    const float* W1  = (const float*)d_in[9];
    const float* b1  = (const float*)d_in[10];
    const float* W2  = (const float*)d_in[11];
    const float* b2  = (const float*)d_in[12];
    float* out = (float*)d_out;

    char* ws = (char*)d_ws;
    __hip_bfloat16* Wct = (__hip_bfloat16*)ws; ws += (size_t)B_ * NC_ * D_ * 2;   // 9.44 MB
    float* c_p = (float*)ws;                   ws += (size_t)B_ * D_ * 4;
    float* c_t = (float*)ws;                   ws += (size_t)B_ * D_ * 4;
    __hip_bfloat16* qb = (__hip_bfloat16*)ws;  ws += (size_t)B_ * T_ * D_ * 2;    // 39.3 MB
    __hip_bfloat16* ps = (__hip_bfloat16*)ws;  ws += (size_t)B_ * T_ * D_ * 2;    // 39.3 MB
    __hip_bfloat16* ts = (__hip_bfloat16*)ws;  ws += (size_t)B_ * T_ * D_ * 2;    // 39.3 MB
    __hip_bfloat16* sm = (__hip_bfloat16*)ws;  ws += (size_t)B_ * G_ * TPP_ * D_ * 2;  // 3.93 MB
    __hip_bfloat16* smW = (__hip_bfloat16*)ws; ws += (size_t)B_ * G_ * TPP_ * D_ * 2;  // 3.93 MB
    __hip_bfloat16* W1at = (__hip_bfloat16*)ws; ws += (size_t)D_ * D_ * 2;        // 1.18 MB
    __hip_bfloat16* W1bt = (__hip_bfloat16*)ws; ws += (size_t)D_ * D_ * 2;        // 1.18 MB

    prep_wct<<<dim3(NC_ / 64, D_ / 64, B_), 256, 0, stream>>>(answer, W_p, W_t, Wct);
    prep_const<<<dim3(B_, D_ / 64), 512, 0, stream>>>(answer, W_p, b_p, W_t, b_t, c_p, c_t);
    conv_q<<<(B_ * T_ * D_) / (256 * 4), 256, 0, stream>>>(qps, qb);
    prep_w1t<<<dim3(D_ / 64, NC_ / 64), 256, 0, stream>>>(W1, W1at, W1bt);
    gemm_pt_mfma<<<dim3(T_ / 128, NC_ / 128, B_), 256, 0, stream>>>(
        qb, Wct, c_p, c_t, ps, ts);
    segmax_kernel<<<(B_ * TPP_ * D_) / 256, 256, 0, stream>>>(ts, tids, sm);
    gemm_smw<<<dim3((B_ * G_ * TPP_) / 128, D_ / 128), 256, 0, stream>>>(sm, W1bt, smW);
    out_init<<<(B_ * P_ + 255) / 256, 256, 0, stream>>>(mask, b2, out);
    gemm_h_fused<<<dim3(T_ / 128, D_ / 128, B_), 256, 0, stream>>>(
        ps, smW, tids, W1at, b1, W2, mask, out);
}